// Round 4
// baseline (225.721 us; speedup 1.0000x reference)
//
#include <hip/hip_runtime.h>
#include <stdint.h>
#include <math.h>

#define SEQ 4096
#define DM  1024
#define NH  16
#define DH  64
#define KPAD 72
#define PPAD 72
#define LOG2E 1.44269504088896341f

typedef short bf16x8 __attribute__((ext_vector_type(8)));
typedef short bf16x4 __attribute__((ext_vector_type(4)));
typedef float f32x4  __attribute__((ext_vector_type(4)));

typedef const __attribute__((address_space(1))) short* gptr_t;
typedef __attribute__((address_space(3))) short* lptr_t;

__device__ __forceinline__ short f2bf(float f) {
    union { float f; uint32_t u; } x; x.f = f;
    uint32_t r = (x.u + 0x7fffu + ((x.u >> 16) & 1u)) >> 16;
    return (short)r;
}
__device__ __forceinline__ short f2bf_trunc(float f) {
    union { float f; uint32_t u; } x; x.f = f;
    return (short)(x.u >> 16);
}

__device__ __forceinline__ void load_lds16(const short* g, const short* l) {
    __builtin_amdgcn_global_load_lds((gptr_t)(uintptr_t)g,
                                     (lptr_t)(uint32_t)(uintptr_t)l, 16, 0, 0);
}

// ---- prep: x fp32 -> bf16 ----
__global__ __launch_bounds__(256) void cvt_x(const float* __restrict__ x,
                                             short* __restrict__ xb) {
    const int i = (blockIdx.x * 256 + threadIdx.x) * 8;
    float4 a = ((const float4*)(x + i))[0];
    float4 b = ((const float4*)(x + i))[1];
    bf16x8 p;
    p[0]=f2bf(a.x); p[1]=f2bf(a.y); p[2]=f2bf(a.z); p[3]=f2bf(a.w);
    p[4]=f2bf(b.x); p[5]=f2bf(b.y); p[6]=f2bf(b.z); p[7]=f2bf(b.w);
    *(bf16x8*)(xb + i) = p;
}

// ---- prep: w [1024][3072] fp32 -> wtb [3072][1024] bf16 (transposed),
//      Q columns pre-scaled by log2e/32 ----
__global__ __launch_bounds__(256) void cvt_wt(const float* __restrict__ w,
                                              short* __restrict__ wtb) {
    __shared__ float T[64][69];
    const int n0 = blockIdx.x * 64, k0 = blockIdx.y * 64;
    const int t = threadIdx.x;
    {
        const int kr = t >> 4, nc = (t & 15) * 4;
        #pragma unroll
        for (int i = 0; i < 4; ++i) {
            float4 v = *(const float4*)(w + (size_t)(k0 + kr + i * 16) * 3072 + n0 + nc);
            T[kr + i * 16][nc + 0] = v.x; T[kr + i * 16][nc + 1] = v.y;
            T[kr + i * 16][nc + 2] = v.z; T[kr + i * 16][nc + 3] = v.w;
        }
    }
    __syncthreads();
    const int nr = t >> 4, kc = (t & 15) * 4;
    #pragma unroll
    for (int i = 0; i < 4; ++i) {
        const int n = n0 + nr + i * 16;
        const float sc = (n >= 1024 && n < 2048) ? (LOG2E / 32.0f) : 1.0f;
        short4 o;
        o.x = f2bf(T[kc + 0][nr + i * 16] * sc);
        o.y = f2bf(T[kc + 1][nr + i * 16] * sc);
        o.z = f2bf(T[kc + 2][nr + i * 16] * sc);
        o.w = f2bf(T[kc + 3][nr + i * 16] * sc);
        *(short4*)(wtb + (size_t)n * 1024 + k0 + kc) = o;
    }
}

// ---- QKV GEMM (m97 structure): 128x128 tile, BK=64, global_load_lds ----
// Block order: x = row-tile (fast), y = col-tile -> same-XCD blocks share B panel.
__global__ __launch_bounds__(256) void qkv_gemm(const short* __restrict__ xb,
                                                const short* __restrict__ wtb,
                                                short* __restrict__ kq,
                                                short* __restrict__ vt) {
    __shared__ short As[128 * 64];
    __shared__ short Bs[128 * 64];
    const int col0 = blockIdx.y * 128, row0 = blockIdx.x * 128;
    const int tid = threadIdx.x, w = tid >> 6, lane = tid & 63;
    const int lmod = lane & 15, ldiv = lane >> 4;
    const int wr = (w >> 1) * 64, wc = (w & 1) * 64;

    f32x4 acc[4][4] = {};
    const short* Ag = xb  + (size_t)row0 * DM;
    const short* Bg = wtb + (size_t)col0 * DM;

    for (int k0 = 0; k0 < DM; k0 += 64) {
        __syncthreads();
        #pragma unroll
        for (int t = 0; t < 4; ++t) {
            const int o = (w * 4 + t) * 1024 + lane * 16;
            const int r = o >> 7, cs = (o & 127) >> 1;
            load_lds16(Ag + (size_t)r * DM + k0 + cs, As + (w * 4 + t) * 512);
            load_lds16(Bg + (size_t)r * DM + k0 + cs, Bs + (w * 4 + t) * 512);
        }
        __syncthreads();
        #pragma unroll
        for (int ks = 0; ks < 2; ++ks) {
            bf16x8 af[4], bf[4];
            #pragma unroll
            for (int i = 0; i < 4; ++i)
                af[i] = *(const bf16x8*)(As + (wr + i * 16 + lmod) * 64 + ks * 32 + ldiv * 8);
            #pragma unroll
            for (int j = 0; j < 4; ++j)
                bf[j] = *(const bf16x8*)(Bs + (wc + j * 16 + lmod) * 64 + ks * 32 + ldiv * 8);
            #pragma unroll
            for (int i = 0; i < 4; ++i)
                #pragma unroll
                for (int j = 0; j < 4; ++j)
                    acc[i][j] = __builtin_amdgcn_mfma_f32_16x16x32_bf16(af[i], bf[j], acc[i][j], 0, 0, 0);
        }
    }

    if (col0 < 2048) {
        #pragma unroll
        for (int i = 0; i < 4; ++i)
            #pragma unroll
            for (int j = 0; j < 4; ++j)
                #pragma unroll
                for (int r = 0; r < 4; ++r)
                    kq[(size_t)(row0 + wr + i * 16 + ldiv * 4 + r) * 2048
                       + col0 + wc + j * 16 + lmod] = f2bf(acc[i][j][r]);
    } else {
        #pragma unroll
        for (int i = 0; i < 4; ++i) {
            const int ig = row0 + wr + i * 16 + ldiv * 4;
            #pragma unroll
            for (int j = 0; j < 4; ++j) {
                const int cg = col0 + wc + j * 16 + lmod - 2048;
                const int h = cg >> 6, d = cg & 63;
                bf16x4 p;
                p[0]=f2bf(acc[i][j][0]); p[1]=f2bf(acc[i][j][1]);
                p[2]=f2bf(acc[i][j][2]); p[3]=f2bf(acc[i][j][3]);
                *(bf16x4*)(vt + (size_t)(h * 64 + d) * SEQ + ig) = p;
            }
        }
    }
}

// ---- flash attention: 128 q-rows/block, 32 q-rows/wave, ALiBi-in-acc-init,
//      fixed-max exp2 softmax, register-prefetch double-buffered staging ----
__global__ __launch_bounds__(256) void attn(const short* __restrict__ kq,
                                            const short* __restrict__ vt,
                                            float* __restrict__ out) {
    __shared__ short Ks[64 * KPAD];
    __shared__ short Vs[64 * KPAD];
    __shared__ short Ps[4 * 32 * PPAD];

    const int b = blockIdx.x;
    const int qt = 31 - (b >> 4);          // LPT: longest q-tiles first
    const int h  = b & 15;
    const int tid = threadIdx.x, w = tid >> 6, lane = tid & 63;
    const int lmod = lane & 15, ldiv = lane >> 4;
    const float slope2 = exp2f(-0.5f * (float)(h + 1)) * LOG2E;  // slope*log2(e)

    const int srow = tid >> 3;          // staging row 0..31
    const int sch  = (tid & 7) * 8;     // staging 8-short chunk
    const int rowbase = qt * 128 + w * 32;
    short* pw = Ps + w * 32 * PPAD;

    // Q fragments (2 m-blocks x 2 k-steps), resident all loop
    bf16x8 qf[2][2];
    #pragma unroll
    for (int m = 0; m < 2; ++m) {
        const short* qp = kq + (size_t)(rowbase + m * 16 + lmod) * 2048 + 1024 + h * 64;
        qf[m][0] = *(const bf16x8*)(qp + ldiv * 8);
        qf[m][1] = *(const bf16x8*)(qp + 32 + ldiv * 8);
    }
    // per-lane bias pieces: bias(i,j) = slope2*(j-i); j-i = kt*64 + nt*16 - r + db[m]
    int db[2];
    float pre[2][4];
    #pragma unroll
    for (int m = 0; m < 2; ++m) {
        db[m] = lmod - (rowbase + m * 16 + ldiv * 4);
        #pragma unroll
        for (int r = 0; r < 4; ++r) pre[m][r] = slope2 * (float)(db[m] - r);
    }

    f32x4 O[2][4] = {};
    float lsum[2][4] = {};
    const int ktmax = 2 * qt + 1;

    uint4 ka0, ka1, va0, va1, kb0, kb1, vb0, vb1;

    auto sload = [&](int kt, uint4& k0, uint4& k1, uint4& v0, uint4& v1) {
        const short* kb_ = kq + (size_t)(kt * 64 + srow) * 2048 + h * 64 + sch;
        k0 = *(const uint4*)kb_;
        k1 = *(const uint4*)(kb_ + (size_t)32 * 2048);
        const short* vb_ = vt + (size_t)(h * 64 + srow) * SEQ + kt * 64 + sch;
        v0 = *(const uint4*)vb_;
        v1 = *(const uint4*)(vb_ + (size_t)32 * SEQ);
    };
    auto swrite = [&](const uint4& k0, const uint4& k1,
                      const uint4& v0, const uint4& v1) {
        *(uint4*)(Ks + srow * KPAD + sch) = k0;
        *(uint4*)(Ks + (srow + 32) * KPAD + sch) = k1;
        *(uint4*)(Vs + srow * KPAD + sch) = v0;
        *(uint4*)(Vs + (srow + 32) * KPAD + sch) = v1;
    };
    auto compute = [&](int kt, bool diag) {
        // init accumulators with ALiBi bias (free: replaces zero-init)
        const float cb = slope2 * (float)(kt * 64);
        f32x4 s[2][4];
        #pragma unroll
        for (int nt = 0; nt < 4; ++nt) {
            const float cn = cb + slope2 * (float)(nt * 16);
            #pragma unroll
            for (int m = 0; m < 2; ++m)
                #pragma unroll
                for (int r = 0; r < 4; ++r) s[m][nt][r] = pre[m][r] + cn;
        }
        // S = Q K^T  (each K frag feeds 2 m-blocks)
        #pragma unroll
        for (int ks = 0; ks < 2; ++ks)
            #pragma unroll
            for (int nt = 0; nt < 4; ++nt) {
                bf16x8 kf = *(const bf16x8*)(Ks + (nt * 16 + lmod) * KPAD + ks * 32 + ldiv * 8);
                #pragma unroll
                for (int m = 0; m < 2; ++m)
                    s[m][nt] = __builtin_amdgcn_mfma_f32_16x16x32_bf16(qf[m][ks], kf, s[m][nt], 0, 0, 0);
            }
        // exp2 + row-sum + P store (truncating bf16)
        const int dt = kt * 64;
        #pragma unroll
        for (int m = 0; m < 2; ++m)
            #pragma unroll
            for (int nt = 0; nt < 4; ++nt)
                #pragma unroll
                for (int r = 0; r < 4; ++r) {
                    float v = s[m][nt][r];
                    if (diag && (dt + nt * 16 - r + db[m] > 0)) v = -1e30f;
                    const float p = __builtin_amdgcn_exp2f(v);
                    lsum[m][r] += p;
                    pw[(m * 16 + ldiv * 4 + r) * PPAD + nt * 16 + lmod] = f2bf_trunc(p);
                }
        // P: same-wave LDS RAW (lgkmcnt ordering, no barrier)
        bf16x8 pa[2][2];
        #pragma unroll
        for (int m = 0; m < 2; ++m) {
            pa[m][0] = *(const bf16x8*)(pw + (m * 16 + lmod) * PPAD + ldiv * 8);
            pa[m][1] = *(const bf16x8*)(pw + (m * 16 + lmod) * PPAD + 32 + ldiv * 8);
        }
        // O += P V  (each V frag feeds 2 m-blocks)
        #pragma unroll
        for (int ks = 0; ks < 2; ++ks)
            #pragma unroll
            for (int nt = 0; nt < 4; ++nt) {
                bf16x8 vf = *(const bf16x8*)(Vs + (nt * 16 + lmod) * KPAD + ks * 32 + ldiv * 8);
                #pragma unroll
                for (int m = 0; m < 2; ++m)
                    O[m][nt] = __builtin_amdgcn_mfma_f32_16x16x32_bf16(pa[m][ks], vf, O[m][nt], 0, 0, 0);
            }
    };

    sload(0, ka0, ka1, va0, va1);
    int kt = 0;
    while (true) {
        if (kt < ktmax) sload(kt + 1, kb0, kb1, vb0, vb1);
        __syncthreads();
        swrite(ka0, ka1, va0, va1);
        __syncthreads();
        compute(kt, kt >= 2 * qt);
        if (++kt > ktmax) break;
        if (kt < ktmax) sload(kt + 1, ka0, ka1, va0, va1);
        __syncthreads();
        swrite(kb0, kb1, vb0, vb1);
        __syncthreads();
        compute(kt, kt >= 2 * qt);
        if (++kt > ktmax) break;
    }

    // reduce row sums across 16-lane groups, write out
    #pragma unroll
    for (int m = 0; m < 2; ++m)
        #pragma unroll
        for (int r = 0; r < 4; ++r) {
            float v = lsum[m][r];
            v += __shfl_xor(v, 1, 16);
            v += __shfl_xor(v, 2, 16);
            v += __shfl_xor(v, 4, 16);
            v += __shfl_xor(v, 8, 16);
            lsum[m][r] = 1.0f / v;
        }
    #pragma unroll
    for (int m = 0; m < 2; ++m) {
        const int i0 = rowbase + m * 16 + ldiv * 4;
        #pragma unroll
        for (int nt = 0; nt < 4; ++nt)
            #pragma unroll
            for (int r = 0; r < 4; ++r)
                out[(size_t)(i0 + r) * DM + h * 64 + nt * 16 + lmod] = O[m][nt][r] * lsum[m][r];
    }
}

extern "C" void kernel_launch(void* const* d_in, const int* in_sizes, int n_in,
                              void* d_out, int out_size, void* d_ws, size_t ws_size,
                              hipStream_t stream) {
    const float* x = (const float*)d_in[0];   // [1,4096,1024] fp32
    const float* w = (const float*)d_in[1];   // [1024,3072] fp32
    float* out = (float*)d_out;

    char* ws = (char*)d_ws;
    short* xb  = (short*)(ws);                        //  8 MB: x bf16
    short* wtb = (short*)(ws + ((size_t)8  << 20));   //  6 MB: w^T bf16 (Q-scaled)
    short* kq  = (short*)(ws + ((size_t)14 << 20));   // 16 MB: K|Q [4096][2048]
    short* vt  = (short*)(ws + ((size_t)30 << 20));   //  8 MB: V^T [16][64][4096]

    cvt_x  <<<SEQ * DM / (256 * 8), 256, 0, stream>>>(x, xb);
    cvt_wt <<<dim3(3072 / 64, 1024 / 64), 256, 0, stream>>>(w, wtb);
    qkv_gemm<<<dim3(SEQ / 128, 3072 / 128), 256, 0, stream>>>(xb, wtb, kq, vt);
    attn   <<<32 * NH, 256, 0, stream>>>(kq, vt, out);
}

// Round 5
// 224.583 us; speedup vs baseline: 1.0051x; 1.0051x over previous
//
#include <hip/hip_runtime.h>
#include <stdint.h>
#include <math.h>

#define SEQ 4096
#define DM  1024
#define NH  16
#define DH  64
#define KPAD 72
#define PPAD 72
#define LOG2E 1.44269504088896341f

typedef short bf16x8 __attribute__((ext_vector_type(8)));
typedef short bf16x4 __attribute__((ext_vector_type(4)));
typedef float f32x4  __attribute__((ext_vector_type(4)));

typedef const __attribute__((address_space(1))) short* gptr_t;
typedef __attribute__((address_space(3))) short* lptr_t;

__device__ __forceinline__ short f2bf(float f) {
    union { float f; uint32_t u; } x; x.f = f;
    uint32_t r = (x.u + 0x7fffu + ((x.u >> 16) & 1u)) >> 16;
    return (short)r;
}
__device__ __forceinline__ short f2bf_trunc(float f) {
    union { float f; uint32_t u; } x; x.f = f;
    return (short)(x.u >> 16);
}

__device__ __forceinline__ void load_lds16(const short* g, const short* l) {
    __builtin_amdgcn_global_load_lds((gptr_t)(uintptr_t)g,
                                     (lptr_t)(uint32_t)(uintptr_t)l, 16, 0, 0);
}

// ---- fused prep: blocks [0,2048) convert x fp32->bf16; blocks [2048,2816)
//      transpose w [1024][3072] -> wtb [3072][1024] bf16, Q cols pre-scaled ----
__global__ __launch_bounds__(256) void cvt_fused(const float* __restrict__ x,
                                                 const float* __restrict__ w,
                                                 short* __restrict__ xb,
                                                 short* __restrict__ wtb) {
    __shared__ float T[64][69];
    const int b = blockIdx.x;
    if (b < 2048) {
        const int i = (b * 256 + threadIdx.x) * 8;
        float4 a0 = ((const float4*)(x + i))[0];
        float4 a1 = ((const float4*)(x + i))[1];
        bf16x8 p;
        p[0]=f2bf(a0.x); p[1]=f2bf(a0.y); p[2]=f2bf(a0.z); p[3]=f2bf(a0.w);
        p[4]=f2bf(a1.x); p[5]=f2bf(a1.y); p[6]=f2bf(a1.z); p[7]=f2bf(a1.w);
        *(bf16x8*)(xb + i) = p;
        return;
    }
    const int bb = b - 2048;
    const int n0 = (bb % 48) * 64, k0 = (bb / 48) * 64;
    const int t = threadIdx.x;
    {
        const int kr = t >> 4, nc = (t & 15) * 4;
        #pragma unroll
        for (int i = 0; i < 4; ++i) {
            float4 v = *(const float4*)(w + (size_t)(k0 + kr + i * 16) * 3072 + n0 + nc);
            T[kr + i * 16][nc + 0] = v.x; T[kr + i * 16][nc + 1] = v.y;
            T[kr + i * 16][nc + 2] = v.z; T[kr + i * 16][nc + 3] = v.w;
        }
    }
    __syncthreads();
    const int nr = t >> 4, kc = (t & 15) * 4;
    #pragma unroll
    for (int i = 0; i < 4; ++i) {
        const int n = n0 + nr + i * 16;
        const float sc = (n >= 1024 && n < 2048) ? (LOG2E / 32.0f) : 1.0f;
        short4 o;
        o.x = f2bf(T[kc + 0][nr + i * 16] * sc);
        o.y = f2bf(T[kc + 1][nr + i * 16] * sc);
        o.z = f2bf(T[kc + 2][nr + i * 16] * sc);
        o.w = f2bf(T[kc + 3][nr + i * 16] * sc);
        *(short4*)(wtb + (size_t)n * 1024 + k0 + kc) = o;
    }
}

// ---- QKV GEMM (m97 structure): 128x128 tile, BK=64, global_load_lds ----
__global__ __launch_bounds__(256) void qkv_gemm(const short* __restrict__ xb,
                                                const short* __restrict__ wtb,
                                                short* __restrict__ kq,
                                                short* __restrict__ vt) {
    __shared__ short As[128 * 64];
    __shared__ short Bs[128 * 64];
    const int col0 = blockIdx.y * 128, row0 = blockIdx.x * 128;
    const int tid = threadIdx.x, w = tid >> 6, lane = tid & 63;
    const int lmod = lane & 15, ldiv = lane >> 4;
    const int wr = (w >> 1) * 64, wc = (w & 1) * 64;

    f32x4 acc[4][4] = {};
    const short* Ag = xb  + (size_t)row0 * DM;
    const short* Bg = wtb + (size_t)col0 * DM;

    for (int k0 = 0; k0 < DM; k0 += 64) {
        __syncthreads();
        #pragma unroll
        for (int t = 0; t < 4; ++t) {
            const int o = (w * 4 + t) * 1024 + lane * 16;
            const int r = o >> 7, cs = (o & 127) >> 1;
            load_lds16(Ag + (size_t)r * DM + k0 + cs, As + (w * 4 + t) * 512);
            load_lds16(Bg + (size_t)r * DM + k0 + cs, Bs + (w * 4 + t) * 512);
        }
        __syncthreads();
        #pragma unroll
        for (int ks = 0; ks < 2; ++ks) {
            bf16x8 af[4], bf[4];
            #pragma unroll
            for (int i = 0; i < 4; ++i)
                af[i] = *(const bf16x8*)(As + (wr + i * 16 + lmod) * 64 + ks * 32 + ldiv * 8);
            #pragma unroll
            for (int j = 0; j < 4; ++j)
                bf[j] = *(const bf16x8*)(Bs + (wc + j * 16 + lmod) * 64 + ks * 32 + ldiv * 8);
            #pragma unroll
            for (int i = 0; i < 4; ++i)
                #pragma unroll
                for (int j = 0; j < 4; ++j)
                    acc[i][j] = __builtin_amdgcn_mfma_f32_16x16x32_bf16(af[i], bf[j], acc[i][j], 0, 0, 0);
        }
    }

    if (col0 < 2048) {
        #pragma unroll
        for (int i = 0; i < 4; ++i)
            #pragma unroll
            for (int j = 0; j < 4; ++j)
                #pragma unroll
                for (int r = 0; r < 4; ++r)
                    kq[(size_t)(row0 + wr + i * 16 + ldiv * 4 + r) * 2048
                       + col0 + wc + j * 16 + lmod] = f2bf(acc[i][j][r]);
    } else {
        #pragma unroll
        for (int i = 0; i < 4; ++i) {
            const int ig = row0 + wr + i * 16 + ldiv * 4;
            #pragma unroll
            for (int j = 0; j < 4; ++j) {
                const int cg = col0 + wc + j * 16 + lmod - 2048;
                const int h = cg >> 6, d = cg & 63;
                bf16x4 p;
                p[0]=f2bf(acc[i][j][0]); p[1]=f2bf(acc[i][j][1]);
                p[2]=f2bf(acc[i][j][2]); p[3]=f2bf(acc[i][j][3]);
                *(bf16x4*)(vt + (size_t)(h * 64 + d) * SEQ + ig) = p;
            }
        }
    }
}

// ---- flash attention: 128 q-rows/block, 32 q-rows/wave, ALiBi-in-acc-init,
//      fixed-max exp2 softmax, register-prefetch double-buffered staging.
//      Balanced grid: blocks b and b+256 (same CU) have qt summing to 31
//      -> every CU does exactly 66 tile-units, heavy-first (LPT). ----
__global__ __launch_bounds__(256) void attn(const short* __restrict__ kq,
                                            const short* __restrict__ vt,
                                            float* __restrict__ out) {
    __shared__ short Ks[64 * KPAD];
    __shared__ short Vs[64 * KPAD];
    __shared__ short Ps[4 * 32 * PPAD];

    const int b = blockIdx.x;
    const int g = b >> 4;
    const int qt = (g < 16) ? (31 - g) : (g - 16);   // complementary pairing
    const int h  = b & 15;
    const int tid = threadIdx.x, w = tid >> 6, lane = tid & 63;
    const int lmod = lane & 15, ldiv = lane >> 4;
    const float slope2 = exp2f(-0.5f * (float)(h + 1)) * LOG2E;  // slope*log2(e)

    const int srow = tid >> 3;          // staging row 0..31
    const int sch  = (tid & 7) * 8;     // staging 8-short chunk
    const int rowbase = qt * 128 + w * 32;
    short* pw = Ps + w * 32 * PPAD;

    // Q fragments (2 m-blocks x 2 k-steps), resident all loop
    bf16x8 qf[2][2];
    #pragma unroll
    for (int m = 0; m < 2; ++m) {
        const short* qp = kq + (size_t)(rowbase + m * 16 + lmod) * 2048 + 1024 + h * 64;
        qf[m][0] = *(const bf16x8*)(qp + ldiv * 8);
        qf[m][1] = *(const bf16x8*)(qp + 32 + ldiv * 8);
    }
    // per-lane bias pieces: bias(i,j) = slope2*(j-i); j-i = kt*64 + nt*16 - r + db[m]
    int db[2];
    float pre[2][4];
    #pragma unroll
    for (int m = 0; m < 2; ++m) {
        db[m] = lmod - (rowbase + m * 16 + ldiv * 4);
        #pragma unroll
        for (int r = 0; r < 4; ++r) pre[m][r] = slope2 * (float)(db[m] - r);
    }

    f32x4 O[2][4] = {};
    float lsum[2][4] = {};
    const int ktmax = 2 * qt + 1;

    uint4 ka0, ka1, va0, va1, kb0, kb1, vb0, vb1;

    auto sload = [&](int kt, uint4& k0, uint4& k1, uint4& v0, uint4& v1) {
        const short* kb_ = kq + (size_t)(kt * 64 + srow) * 2048 + h * 64 + sch;
        k0 = *(const uint4*)kb_;
        k1 = *(const uint4*)(kb_ + (size_t)32 * 2048);
        const short* vb_ = vt + (size_t)(h * 64 + srow) * SEQ + kt * 64 + sch;
        v0 = *(const uint4*)vb_;
        v1 = *(const uint4*)(vb_ + (size_t)32 * SEQ);
    };
    auto swrite = [&](const uint4& k0, const uint4& k1,
                      const uint4& v0, const uint4& v1) {
        *(uint4*)(Ks + srow * KPAD + sch) = k0;
        *(uint4*)(Ks + (srow + 32) * KPAD + sch) = k1;
        *(uint4*)(Vs + srow * KPAD + sch) = v0;
        *(uint4*)(Vs + (srow + 32) * KPAD + sch) = v1;
    };
    auto compute = [&](int kt, bool diag) {
        // init accumulators with ALiBi bias (free: replaces zero-init)
        const float cb = slope2 * (float)(kt * 64);
        f32x4 s[2][4];
        #pragma unroll
        for (int nt = 0; nt < 4; ++nt) {
            const float cn = cb + slope2 * (float)(nt * 16);
            #pragma unroll
            for (int m = 0; m < 2; ++m)
                #pragma unroll
                for (int r = 0; r < 4; ++r) s[m][nt][r] = pre[m][r] + cn;
        }
        // S = Q K^T  (each K frag feeds 2 m-blocks)
        #pragma unroll
        for (int ks = 0; ks < 2; ++ks)
            #pragma unroll
            for (int nt = 0; nt < 4; ++nt) {
                bf16x8 kf = *(const bf16x8*)(Ks + (nt * 16 + lmod) * KPAD + ks * 32 + ldiv * 8);
                #pragma unroll
                for (int m = 0; m < 2; ++m)
                    s[m][nt] = __builtin_amdgcn_mfma_f32_16x16x32_bf16(qf[m][ks], kf, s[m][nt], 0, 0, 0);
            }
        // exp2 + row-sum + P store (truncating bf16)
        const int dt = kt * 64;
        #pragma unroll
        for (int m = 0; m < 2; ++m)
            #pragma unroll
            for (int nt = 0; nt < 4; ++nt)
                #pragma unroll
                for (int r = 0; r < 4; ++r) {
                    float v = s[m][nt][r];
                    if (diag && (dt + nt * 16 - r + db[m] > 0)) v = -1e30f;
                    const float p = __builtin_amdgcn_exp2f(v);
                    lsum[m][r] += p;
                    pw[(m * 16 + ldiv * 4 + r) * PPAD + nt * 16 + lmod] = f2bf_trunc(p);
                }
        // P: same-wave LDS RAW (lgkmcnt ordering, no barrier)
        bf16x8 pa[2][2];
        #pragma unroll
        for (int m = 0; m < 2; ++m) {
            pa[m][0] = *(const bf16x8*)(pw + (m * 16 + lmod) * PPAD + ldiv * 8);
            pa[m][1] = *(const bf16x8*)(pw + (m * 16 + lmod) * PPAD + 32 + ldiv * 8);
        }
        // O += P V  (each V frag feeds 2 m-blocks)
        #pragma unroll
        for (int ks = 0; ks < 2; ++ks)
            #pragma unroll
            for (int nt = 0; nt < 4; ++nt) {
                bf16x8 vf = *(const bf16x8*)(Vs + (nt * 16 + lmod) * KPAD + ks * 32 + ldiv * 8);
                #pragma unroll
                for (int m = 0; m < 2; ++m)
                    O[m][nt] = __builtin_amdgcn_mfma_f32_16x16x32_bf16(pa[m][ks], vf, O[m][nt], 0, 0, 0);
            }
    };

    sload(0, ka0, ka1, va0, va1);
    int kt = 0;
    while (true) {
        if (kt < ktmax) sload(kt + 1, kb0, kb1, vb0, vb1);
        __syncthreads();
        swrite(ka0, ka1, va0, va1);
        __syncthreads();
        compute(kt, kt >= 2 * qt);
        if (++kt > ktmax) break;
        if (kt < ktmax) sload(kt + 1, ka0, ka1, va0, va1);
        __syncthreads();
        swrite(kb0, kb1, vb0, vb1);
        __syncthreads();
        compute(kt, kt >= 2 * qt);
        if (++kt > ktmax) break;
    }

    // reduce row sums across 16-lane groups, write out
    #pragma unroll
    for (int m = 0; m < 2; ++m)
        #pragma unroll
        for (int r = 0; r < 4; ++r) {
            float v = lsum[m][r];
            v += __shfl_xor(v, 1, 16);
            v += __shfl_xor(v, 2, 16);
            v += __shfl_xor(v, 4, 16);
            v += __shfl_xor(v, 8, 16);
            lsum[m][r] = 1.0f / v;
        }
    #pragma unroll
    for (int m = 0; m < 2; ++m) {
        const int i0 = rowbase + m * 16 + ldiv * 4;
        #pragma unroll
        for (int nt = 0; nt < 4; ++nt)
            #pragma unroll
            for (int r = 0; r < 4; ++r)
                out[(size_t)(i0 + r) * DM + h * 64 + nt * 16 + lmod] = O[m][nt][r] * lsum[m][r];
    }
}

extern "C" void kernel_launch(void* const* d_in, const int* in_sizes, int n_in,
                              void* d_out, int out_size, void* d_ws, size_t ws_size,
                              hipStream_t stream) {
    const float* x = (const float*)d_in[0];   // [1,4096,1024] fp32
    const float* w = (const float*)d_in[1];   // [1024,3072] fp32
    float* out = (float*)d_out;

    char* ws = (char*)d_ws;
    short* xb  = (short*)(ws);                        //  8 MB: x bf16
    short* wtb = (short*)(ws + ((size_t)8  << 20));   //  6 MB: w^T bf16 (Q-scaled)
    short* kq  = (short*)(ws + ((size_t)14 << 20));   // 16 MB: K|Q [4096][2048]
    short* vt  = (short*)(ws + ((size_t)30 << 20));   //  8 MB: V^T [16][64][4096]

    cvt_fused<<<2048 + 768, 256, 0, stream>>>(x, w, xb, wtb);
    qkv_gemm <<<dim3(SEQ / 128, 3072 / 128), 256, 0, stream>>>(xb, wtb, kq, vt);
    attn     <<<32 * NH, 256, 0, stream>>>(kq, vt, out);
}